// Round 1
// baseline (755.399 us; speedup 1.0000x reference)
//
#include <hip/hip_runtime.h>
#include <math.h>

#define NA 2048
#define CA 128
#define CP 16
#define NH 4
#define CH 32

// ---------------- Kernel 1: LN(ql) + q/k/v/gate projections ----------------
__global__ __launch_bounds__(256) void qkvg_kernel(
    const float* __restrict__ ql,
    const float* __restrict__ nqw, const float* __restrict__ nqb,
    const float* __restrict__ Wq, const float* __restrict__ bq,
    const float* __restrict__ Wk, const float* __restrict__ Wv,
    const float* __restrict__ Wg,
    float* __restrict__ q_out, float* __restrict__ k_out,
    float* __restrict__ v_out, float* __restrict__ g_out)
{
    __shared__ float x_lds[8 * 128];
    __shared__ float ln_lds[8 * 128];
    const int t = threadIdx.x;
    const int row0 = blockIdx.x * 8;

    for (int idx = t; idx < 1024; idx += 256)
        x_lds[idx] = ql[(size_t)row0 * 128 + idx];
    __syncthreads();

    // LayerNorm per row: 32 lanes per row, 4 elems per lane
    {
        const int r = t >> 5, id = t & 31;
        float4 x4 = ((const float4*)x_lds)[r * 32 + id];
        float s = x4.x + x4.y + x4.z + x4.w;
        float s2 = x4.x * x4.x + x4.y * x4.y + x4.z * x4.z + x4.w * x4.w;
#pragma unroll
        for (int mask = 16; mask >= 1; mask >>= 1) {
            s += __shfl_xor(s, mask);
            s2 += __shfl_xor(s2, mask);
        }
        const float mu = s * (1.0f / 128.0f);
        const float inv = rsqrtf(s2 * (1.0f / 128.0f) - mu * mu + 1e-5f);
#pragma unroll
        for (int k = 0; k < 4; ++k) {
            const int c = id * 4 + k;
            const float xv = x_lds[r * 128 + c];
            ln_lds[r * 128 + c] = (xv - mu) * inv * nqw[c] + nqb[c];
        }
    }
    __syncthreads();

    // Fused GEMV: 512 output cols (4 matrices x 128), 2 cols per thread
#pragma unroll
    for (int cc = 0; cc < 2; ++cc) {
        const int col = t + cc * 256;
        const int m = col >> 7;        // wave-uniform
        const int cl = col & 127;
        const float* W = (m == 0) ? Wq : (m == 1) ? Wk : (m == 2) ? Wv : Wg;
        float acc[8] = {0, 0, 0, 0, 0, 0, 0, 0};
        const float4* Wrow = (const float4*)(W + (size_t)cl * 128);
#pragma unroll 8
        for (int k4 = 0; k4 < 32; ++k4) {
            const float4 w4 = Wrow[k4];
#pragma unroll
            for (int rr = 0; rr < 8; ++rr) {
                const float4 l4 = ((const float4*)ln_lds)[rr * 32 + k4];
                acc[rr] += l4.x * w4.x + l4.y * w4.y + l4.z * w4.z + l4.w * w4.w;
            }
        }
        float* outp;
        if (m == 0) {
            const float bb = bq[cl];
#pragma unroll
            for (int rr = 0; rr < 8; ++rr) acc[rr] = (acc[rr] + bb) * 0.17677669529663687f; // 1/sqrt(32)
            outp = q_out;
        } else if (m == 1) {
            outp = k_out;
        } else if (m == 2) {
            outp = v_out;
        } else {
#pragma unroll
            for (int rr = 0; rr < 8; ++rr) acc[rr] = 1.0f / (1.0f + __expf(-acc[rr]));
            outp = g_out;
        }
#pragma unroll
        for (int rr = 0; rr < 8; ++rr)
            outp[(size_t)(row0 + rr) * 128 + cl] = acc[rr];
    }
}

// ---------------- Kernel 2: pair bias + attention (one block per query row) ----------------
__global__ __launch_bounds__(256) void attn_kernel(
    const float* __restrict__ plm, const float* __restrict__ beta_mask,
    const float* __restrict__ npw, const float* __restrict__ npb,
    const float* __restrict__ Wpb,
    const float* __restrict__ q_ws, const float* __restrict__ k_ws,
    const float* __restrict__ v_ws, const float* __restrict__ g_ws,
    float* __restrict__ attn_g)
{
    __shared__ float logit[NH * NA];   // 32 KiB
    __shared__ float qrow[128];
    __shared__ float wpb_s[64];
    __shared__ float npw_s[16], npb_s[16];

    const int t = threadIdx.x;
    const int i = blockIdx.x;
    const int h = t >> 6;
    const int lane = t & 63;

    if (t < 128) qrow[t] = q_ws[(size_t)i * 128 + t];
    if (t < 64) wpb_s[t] = Wpb[t];
    if (t < 16) { npw_s[t] = npw[t]; npb_s[t] = npb[t]; }
    __syncthreads();

    // Phase A: pair-bias LN + Wpb proj + beta_mask -> logit LDS
    const size_t plm_row = (size_t)i * NA * CP;
    for (int j = t; j < NA; j += 256) {
        const float4* p4 = (const float4*)(plm + plm_row + (size_t)j * CP);
        const float4 a = p4[0], b = p4[1], c = p4[2], d = p4[3];
        float xv[16] = {a.x, a.y, a.z, a.w, b.x, b.y, b.z, b.w,
                        c.x, c.y, c.z, c.w, d.x, d.y, d.z, d.w};
        float s = 0.0f, s2 = 0.0f;
#pragma unroll
        for (int k = 0; k < 16; ++k) { s += xv[k]; s2 += xv[k] * xv[k]; }
        const float mu = s * (1.0f / 16.0f);
        const float inv = rsqrtf(s2 * (1.0f / 16.0f) - mu * mu + 1e-5f);
        float xn[16];
#pragma unroll
        for (int k = 0; k < 16; ++k) xn[k] = (xv[k] - mu) * inv * npw_s[k] + npb_s[k];
        const float bm = beta_mask[(size_t)i * NA + j];
#pragma unroll
        for (int hh = 0; hh < 4; ++hh) {
            float bias = bm;
#pragma unroll
            for (int k = 0; k < 16; ++k) bias += xn[k] * wpb_s[hh * 16 + k];
            logit[hh * NA + j] = bias;
        }
    }
    __syncthreads();

    // Phase B: add q.k (wave h owns head h; lane owns j = it*64+lane)
    float qr[32];
#pragma unroll
    for (int c = 0; c < 32; ++c) qr[c] = qrow[h * 32 + c];
#pragma unroll 4
    for (int it = 0; it < 32; ++it) {
        const int j = it * 64 + lane;
        const float4* krow = (const float4*)(k_ws + (size_t)j * 128 + h * 32);
        float acc = 0.0f;
#pragma unroll
        for (int c4 = 0; c4 < 8; ++c4) {
            const float4 k4 = krow[c4];
            acc += qr[c4 * 4 + 0] * k4.x + qr[c4 * 4 + 1] * k4.y +
                   qr[c4 * 4 + 2] * k4.z + qr[c4 * 4 + 3] * k4.w;
        }
        logit[h * NA + j] += acc;
    }
    __syncthreads();

    // Phase C0: row max per head
    float m = -3.4e38f;
#pragma unroll 8
    for (int it = 0; it < 32; ++it) m = fmaxf(m, logit[h * NA + it * 64 + lane]);
#pragma unroll
    for (int mask = 32; mask >= 1; mask >>= 1) m = fmaxf(m, __shfl_xor(m, mask));

    // Phase C1: p = exp(logit - m), row sum, store p back
    float l = 0.0f;
#pragma unroll 4
    for (int it = 0; it < 32; ++it) {
        const int idx = h * NA + it * 64 + lane;
        const float p = __expf(logit[idx] - m);
        l += p;
        logit[idx] = p;
    }
#pragma unroll
    for (int mask = 32; mask >= 1; mask >>= 1) l += __shfl_xor(l, mask);
    __syncthreads();

    // Phase C2: O = P.V ; lane = jo*8 + cq (8 j-slots x 8 channel-quads)
    const int jo = lane >> 3, cq = lane & 7;
    float4 o = {0, 0, 0, 0};
#pragma unroll 4
    for (int it = 0; it < 256; ++it) {
        const int j = it * 8 + jo;
        const float p = logit[h * NA + j];
        const float4 v4 = *(const float4*)(v_ws + (size_t)j * 128 + h * 32 + cq * 4);
        o.x += p * v4.x; o.y += p * v4.y; o.z += p * v4.z; o.w += p * v4.w;
    }
#pragma unroll
    for (int mask = 8; mask <= 32; mask <<= 1) {
        o.x += __shfl_xor(o.x, mask);
        o.y += __shfl_xor(o.y, mask);
        o.z += __shfl_xor(o.z, mask);
        o.w += __shfl_xor(o.w, mask);
    }
    if (jo == 0) {
        const float invl = 1.0f / l;
        const float4 g4 = *(const float4*)(g_ws + (size_t)i * 128 + h * 32 + cq * 4);
        float4 r;
        r.x = o.x * invl * g4.x;
        r.y = o.y * invl * g4.y;
        r.z = o.z * invl * g4.z;
        r.w = o.w * invl * g4.w;
        *(float4*)(attn_g + (size_t)i * 128 + h * 32 + cq * 4) = r;
    }
}

// ---------------- Kernel 3: Wo proj + residual + LN + MLP + residual ----------------
__global__ __launch_bounds__(256) void out_mlp_kernel(
    const float* __restrict__ ql,
    const float* __restrict__ attn_g,
    const float* __restrict__ Wo,
    const float* __restrict__ tlw, const float* __restrict__ tlb,
    const float* __restrict__ W1, const float* __restrict__ b1,
    const float* __restrict__ W2, const float* __restrict__ b2,
    float* __restrict__ out)
{
    __shared__ float a_lds[8 * 128];
    __shared__ float ql2_lds[8 * 128];
    __shared__ float t_lds[8 * 128];
    __shared__ float h1_lds[8 * 512];
    const int t = threadIdx.x;
    const int row0 = blockIdx.x * 8;

    for (int idx = t; idx < 1024; idx += 256)
        a_lds[idx] = attn_g[(size_t)row0 * 128 + idx];
    __syncthreads();

    const int c = t & 127, half = t >> 7;

    // Stage 1: out = gated_attn @ Wo.T ; ql2 = ql + out
    {
        float acc[4] = {0, 0, 0, 0};
        const float4* wrow = (const float4*)(Wo + (size_t)c * 128);
#pragma unroll 8
        for (int k4 = 0; k4 < 32; ++k4) {
            const float4 w4 = wrow[k4];
#pragma unroll
            for (int rr = 0; rr < 4; ++rr) {
                const float4 a4 = ((const float4*)a_lds)[(half * 4 + rr) * 32 + k4];
                acc[rr] += a4.x * w4.x + a4.y * w4.y + a4.z * w4.z + a4.w * w4.w;
            }
        }
#pragma unroll
        for (int rr = 0; rr < 4; ++rr) {
            const int r = half * 4 + rr;
            ql2_lds[r * 128 + c] = ql[(size_t)(row0 + r) * 128 + c] + acc[rr];
        }
    }
    __syncthreads();

    // LayerNorm(ql2)
    {
        const int r = t >> 5, id = t & 31;
        const float4 x4 = ((const float4*)ql2_lds)[r * 32 + id];
        float s = x4.x + x4.y + x4.z + x4.w;
        float s2 = x4.x * x4.x + x4.y * x4.y + x4.z * x4.z + x4.w * x4.w;
#pragma unroll
        for (int mask = 16; mask >= 1; mask >>= 1) {
            s += __shfl_xor(s, mask);
            s2 += __shfl_xor(s2, mask);
        }
        const float mu = s * (1.0f / 128.0f);
        const float inv = rsqrtf(s2 * (1.0f / 128.0f) - mu * mu + 1e-5f);
#pragma unroll
        for (int k = 0; k < 4; ++k) {
            const int cc = id * 4 + k;
            t_lds[r * 128 + cc] = (ql2_lds[r * 128 + cc] - mu) * inv * tlw[cc] + tlb[cc];
        }
    }
    __syncthreads();

    // Stage 2: h1 = relu(t @ W1.T + b1)
#pragma unroll
    for (int cc = 0; cc < 2; ++cc) {
        const int col = t + cc * 256;
        float acc[8] = {0, 0, 0, 0, 0, 0, 0, 0};
        const float4* wrow = (const float4*)(W1 + (size_t)col * 128);
#pragma unroll 8
        for (int k4 = 0; k4 < 32; ++k4) {
            const float4 w4 = wrow[k4];
#pragma unroll
            for (int rr = 0; rr < 8; ++rr) {
                const float4 a4 = ((const float4*)t_lds)[rr * 32 + k4];
                acc[rr] += a4.x * w4.x + a4.y * w4.y + a4.z * w4.z + a4.w * w4.w;
            }
        }
        const float bb = b1[col];
#pragma unroll
        for (int rr = 0; rr < 8; ++rr)
            h1_lds[rr * 512 + col] = fmaxf(acc[rr] + bb, 0.0f);
    }
    __syncthreads();

    // Stage 3: out = ql2 + h1 @ W2.T + b2
    {
        float acc[4] = {0, 0, 0, 0};
        const float4* wrow = (const float4*)(W2 + (size_t)c * 512);
#pragma unroll 8
        for (int k4 = 0; k4 < 128; ++k4) {
            const float4 w4 = wrow[k4];
#pragma unroll
            for (int rr = 0; rr < 4; ++rr) {
                const float4 a4 = ((const float4*)h1_lds)[(half * 4 + rr) * 128 + k4];
                acc[rr] += a4.x * w4.x + a4.y * w4.y + a4.z * w4.z + a4.w * w4.w;
            }
        }
        const float bb = b2[c];
#pragma unroll
        for (int rr = 0; rr < 4; ++rr) {
            const int r = half * 4 + rr;
            out[(size_t)(row0 + r) * 128 + c] = ql2_lds[r * 128 + c] + acc[rr] + bb;
        }
    }
}

extern "C" void kernel_launch(void* const* d_in, const int* in_sizes, int n_in,
                              void* d_out, int out_size, void* d_ws, size_t ws_size,
                              hipStream_t stream) {
    const float* ql   = (const float*)d_in[0];
    // d_in[1] = cl : unused by the reference
    const float* plm  = (const float*)d_in[2];
    const float* beta = (const float*)d_in[3];
    const float* nqw  = (const float*)d_in[4];
    const float* nqb  = (const float*)d_in[5];
    const float* npw  = (const float*)d_in[6];
    const float* npb  = (const float*)d_in[7];
    const float* Wq   = (const float*)d_in[8];
    const float* bq   = (const float*)d_in[9];
    const float* Wk   = (const float*)d_in[10];
    const float* Wv   = (const float*)d_in[11];
    const float* Wpb  = (const float*)d_in[12];
    const float* Wg   = (const float*)d_in[13];
    const float* Wo   = (const float*)d_in[14];
    const float* tlw  = (const float*)d_in[15];
    const float* tlb  = (const float*)d_in[16];
    const float* W1   = (const float*)d_in[17];
    const float* b1   = (const float*)d_in[18];
    const float* W2   = (const float*)d_in[19];
    const float* b2   = (const float*)d_in[20];
    float* out = (float*)d_out;

    float* ws = (float*)d_ws;
    float* q_ws  = ws;
    float* k_ws  = ws + 1 * 262144;
    float* v_ws  = ws + 2 * 262144;
    float* g_ws  = ws + 3 * 262144;
    float* ag_ws = ws + 4 * 262144;

    qkvg_kernel<<<NA / 8, 256, 0, stream>>>(ql, nqw, nqb, Wq, bq, Wk, Wv, Wg,
                                            q_ws, k_ws, v_ws, g_ws);
    attn_kernel<<<NA, 256, 0, stream>>>(plm, beta, npw, npb, Wpb,
                                        q_ws, k_ws, v_ws, g_ws, ag_ws);
    out_mlp_kernel<<<NA / 8, 256, 0, stream>>>(ql, ag_ws, Wo, tlw, tlb,
                                               W1, b1, W2, b2, out);
}